// Round 5
// baseline (528.263 us; speedup 1.0000x reference)
//
#include <hip/hip_runtime.h>

// ============================================================================
// Fused 2-layer transformer encoder (B=1024, T=128, D=128, H=8, HD=16, FF=512)
// One workgroup per batch element; bf16 MFMA 16x16x32; fp32 accum/softmax/LN.
// All matmuls in transposed orientation (Y^T = W*X^T) -> ushort4 C-stores.
//
// Occupancy revision 3: 1024-thread blocks (16 waves). A single block pins
// 4 waves/SIMD (2x round-1) without needing 2 blocks/CU, so LDS returns to a
// roomy 145 KiB (K, V in LDS; padded strides). The 1024-thread launch bound
// caps regs at 128/thread; per-wave work is HALVED vs the 512-thread design
// (acc arrays 8->4, vfr hoist dropped, mreg eliminated) so the natural peak
// (~95-110) fits without spills -- unlike round 3/4 (~190-reg peak, spilled).
// Work split: A: 48 (tile,half) QKV tasks, 3/wave. B: head=w>>1, 4 q-tiles.
// C/E: col-tile=w>>1, row-half=w&1. FF: 2 chunks of 256; FF1 by-N (16 tiles),
// FF2 by (col-tile, half). Hidden chunk aliases the K|V^T region.
// ============================================================================

typedef __attribute__((ext_vector_type(8))) __bf16 bf16x8;
typedef __attribute__((ext_vector_type(4))) float fx4;

#define MFMA16(a, b, c) __builtin_amdgcn_mfma_f32_16x16x32_bf16((a), (b), (c), 0, 0, 0)

// padded LDS strides (elements); dword stride ≡ 4 mod 32 (R1-proven profile)
#define XS_S 136
#define QS_S 136
#define KS_S 136
#define VT_S 136
#define HS   264

static __device__ __forceinline__ unsigned short f2bf(float f) {
    __bf16 b = (__bf16)f;                       // fptrunc f32->bf16, RTN-even
    return __builtin_bit_cast(unsigned short, b);
}
static __device__ __forceinline__ float bf2f(unsigned short u) {
    return (float)__builtin_bit_cast(__bf16, u);
}
static __device__ __forceinline__ unsigned pk2(float a, float b) {
    return (unsigned)f2bf(a) | ((unsigned)f2bf(b) << 16);
}
static __device__ __forceinline__ bf16x8 mk8(unsigned d0, unsigned d1,
                                             unsigned d2, unsigned d3) {
    union { unsigned u[4]; bf16x8 v; } c;
    c.u[0] = d0; c.u[1] = d1; c.u[2] = d2; c.u[3] = d3;
    return c.v;
}

// --------------------------------------------------------------------------
// Prep: convert all fp32 weights to bf16 into workspace.
// Segments (elements): in_proj 98304 | out 32768 | ff1 131072 | ff2 131072
// --------------------------------------------------------------------------
extern "C" __global__ void prep_weights_bf16(const float* __restrict__ w_in,
                                             const float* __restrict__ w_out,
                                             const float* __restrict__ w_ff1,
                                             const float* __restrict__ w_ff2,
                                             unsigned short* __restrict__ ws) {
    int i = blockIdx.x * 256 + threadIdx.x;     // grid covers exactly 393216
    float v;
    if (i < 98304)       v = w_in[i];
    else if (i < 131072) v = w_out[i - 98304];
    else if (i < 262144) v = w_ff1[i - 131072];
    else                 v = w_ff2[i - 262144];
    ws[i] = f2bf(v);
}

// --------------------------------------------------------------------------
// Main fused kernel. block = 1024 threads = 16 waves. grid = 1024 (one per b).
// 1024 threads => 4 waves/SIMD resident => hard 128-reg cap (by design).
// --------------------------------------------------------------------------
extern "C" __global__ void __launch_bounds__(1024, 1)
fused_transformer(const float* __restrict__ x,
                  const float* __restrict__ mask,
                  const float* __restrict__ inp_b,
                  const float* __restrict__ out_b,
                  const float* __restrict__ ln1g, const float* __restrict__ ln1b,
                  const float* __restrict__ ff1b, const float* __restrict__ ff2b,
                  const float* __restrict__ ln2g, const float* __restrict__ ln2b,
                  const unsigned short* __restrict__ w_inp,
                  const unsigned short* __restrict__ w_out,
                  const unsigned short* __restrict__ w_ff1,
                  const unsigned short* __restrict__ w_ff2,
                  float* __restrict__ out) {
    // 145 KiB static LDS (<= 160 KiB; one block/CU with 16 waves)
    __shared__ __align__(16) unsigned short xs[128 * XS_S];   // x / LN out [t][d]
    __shared__ __align__(16) unsigned short qs[128 * QS_S];   // q -> o      [t][d]
    __shared__ __align__(16) unsigned short kvh[2 * 128 * KS_S]; // k | v^T ; FF hidden
    __shared__ __align__(16) float lnbuf[2304];               // LN scratch, 9 KiB

    unsigned short* ksb = kvh;                 // k   [t][d]    stride KS_S
    unsigned short* vtb = kvh + 128 * KS_S;    // v^T [d][t]    stride VT_S
    unsigned short* hb  = kvh;                 // FF hidden [t][256] stride HS
    float2* lnp = (float2*)lnbuf;              // [8][128] {sum, sumsq}
    float2* mrp = lnp + 1024;                  // [128] {mean, rstd}

    const int tid = threadIdx.x;
    const int w   = tid >> 6;        // wave 0..15
    const int lid = tid & 63;
    const int l15 = lid & 15;
    const int kg  = lid >> 4;        // k-group 0..3
    const int b   = blockIdx.x;
    const int ct  = w >> 1;          // col-tile 0..7 (C/E/FF2); head in B
    const int hf  = w & 1;           // row half 0/1

    // ---- stage x[b] (fp32 global) -> xs (bf16 LDS), coalesced float4 ----
    const float* xb = x + (size_t)b * 16384;
    #pragma unroll
    for (int i = 0; i < 4; ++i) {
        int e = i * 4096 + tid * 4;
        float4 v4 = *(const float4*)(xb + e);
        int row = e >> 7, col = e & 127;
        ushort4 pk;
        pk.x = f2bf(v4.x); pk.y = f2bf(v4.y); pk.z = f2bf(v4.z); pk.w = f2bf(v4.w);
        *(ushort4*)(xs + row * XS_S + col) = pk;
    }
    __syncthreads();

    for (int l = 0; l < 2; ++l) {
        // ========== Phase A: QKV projection, 48 (tile,half) tasks, 3/wave ===
        {
            const unsigned short* wbase = w_inp + (size_t)l * 49152;
            #pragma unroll
            for (int i = 0; i < 3; ++i) {
                int T = w * 3 + i;                 // wave-uniform task id 0..47
                int tile = T >> 1, half = T & 1;   // tile: 0-7 q, 8-15 k, 16-23 v
                bf16x8 wf[4];
                #pragma unroll
                for (int ks = 0; ks < 4; ++ks)
                    wf[ks] = *(const bf16x8*)(wbase + (tile * 16 + l15) * 128
                                              + ks * 32 + kg * 8);
                if (tile < 16) {                   // q or k: Y^T = W * X^T
                    fx4 bs = *(const fx4*)(inp_b + l * 384 + tile * 16 + kg * 4);
                    #pragma unroll
                    for (int j = 0; j < 4; ++j) {
                        int trow = (half * 4 + j) * 16 + l15;
                        bf16x8 xf[4];
                        #pragma unroll
                        for (int ks = 0; ks < 4; ++ks)
                            xf[ks] = *(const bf16x8*)(xs + trow * XS_S + ks * 32 + kg * 8);
                        fx4 a = bs;
                        #pragma unroll
                        for (int ks = 0; ks < 4; ++ks) a = MFMA16(wf[ks], xf[ks], a);
                        ushort4 p4;
                        if (tile < 8) {            // q, pre-scaled by 0.25
                            p4.x = f2bf(a[0] * 0.25f); p4.y = f2bf(a[1] * 0.25f);
                            p4.z = f2bf(a[2] * 0.25f); p4.w = f2bf(a[3] * 0.25f);
                            *(ushort4*)(qs + trow * QS_S + tile * 16 + kg * 4) = p4;
                        } else {                   // k
                            p4.x = f2bf(a[0]); p4.y = f2bf(a[1]);
                            p4.z = f2bf(a[2]); p4.w = f2bf(a[3]);
                            *(ushort4*)(ksb + trow * KS_S + (tile - 8) * 16 + kg * 4) = p4;
                        }
                    }
                } else {                           // v: V = X * Wv^T -> v^T store
                    float bv = inp_b[l * 384 + tile * 16 + l15];
                    #pragma unroll
                    for (int j = 0; j < 4; ++j) {
                        int mt = half * 4 + j;
                        int trow = mt * 16 + l15;
                        bf16x8 xf[4];
                        #pragma unroll
                        for (int ks = 0; ks < 4; ++ks)
                            xf[ks] = *(const bf16x8*)(xs + trow * XS_S + ks * 32 + kg * 8);
                        fx4 a = {bv, bv, bv, bv};
                        #pragma unroll
                        for (int ks = 0; ks < 4; ++ks) a = MFMA16(xf[ks], wf[ks], a);
                        ushort4 p4;
                        p4.x = f2bf(a[0]); p4.y = f2bf(a[1]);
                        p4.z = f2bf(a[2]); p4.w = f2bf(a[3]);
                        *(ushort4*)(vtb + ((tile - 16) * 16 + l15) * VT_S
                                    + mt * 16 + kg * 4) = p4;
                    }
                }
            }
        }
        __syncthreads();

        // ========== Phase B: attention, head = ct, 4 q-tiles per wave =======
        {
            const int h = ct;
            // hoist K fragments (A-operand); kg==2 slot carries the mask
            bf16x8 kfr[8];
            #pragma unroll
            for (int kt = 0; kt < 8; ++kt) {
                bf16x8 f = {};
                if (kg < 2)
                    f = *(const bf16x8*)(ksb + (kt * 16 + l15) * KS_S + h * 16 + kg * 8);
                else if (kg == 2)
                    f[0] = (__bf16)mask[b * 128 + kt * 16 + l15];
                kfr[kt] = f;
            }
            const int sp = (2 * (kg & 1)) * 16 + l15;   // P gather src base
            #pragma unroll 1
            for (int j = 0; j < 4; ++j) {
                int qrow = (hf * 4 + j) * 16 + l15;
                bf16x8 qf = {};
                if (kg < 2) qf = *(const bf16x8*)(qs + qrow * QS_S + h * 16 + kg * 8);
                else if (kg == 2) qf[0] = (__bf16)1.0f;   // ones column -> adds mask
                // S^T tile: lane l15 = query, 32 regs = keys (scaled+masked)
                fx4 sc[8];
                #pragma unroll
                for (int kt = 0; kt < 8; ++kt) {
                    fx4 z = {0.f, 0.f, 0.f, 0.f};
                    sc[kt] = MFMA16(kfr[kt], qf, z);
                }
                // per-lane softmax over 32 regs + 2 shuffles across kg
                float mx = -3.0e38f;
                #pragma unroll
                for (int kt = 0; kt < 8; ++kt)
                    #pragma unroll
                    for (int r = 0; r < 4; ++r) mx = fmaxf(mx, sc[kt][r]);
                mx = fmaxf(mx, __shfl_xor(mx, 16, 64));
                mx = fmaxf(mx, __shfl_xor(mx, 32, 64));
                float sm = 0.f;
                #pragma unroll
                for (int kt = 0; kt < 8; ++kt)
                    #pragma unroll
                    for (int r = 0; r < 4; ++r) {
                        float e = __expf(sc[kt][r] - mx);
                        sc[kt][r] = e;
                        sm += e;
                    }
                sm += __shfl_xor(sm, 16, 64);
                sm += __shfl_xor(sm, 32, 64);
                float inv = 1.f / sm;
                // PV: per 32-key step, gather P^T fragment via 8 shuffles
                fx4 oacc = {0.f, 0.f, 0.f, 0.f};
                #pragma unroll
                for (int s = 0; s < 4; ++s) {
                    bf16x8 vv = *(const bf16x8*)(vtb + (h * 16 + l15) * VT_S
                                                 + s * 32 + kg * 8);
                    unsigned pA0 = pk2(sc[2*s][0] * inv,   sc[2*s][1] * inv);
                    unsigned pA1 = pk2(sc[2*s][2] * inv,   sc[2*s][3] * inv);
                    unsigned pB0 = pk2(sc[2*s+1][0] * inv, sc[2*s+1][1] * inv);
                    unsigned pB1 = pk2(sc[2*s+1][2] * inv, sc[2*s+1][3] * inv);
                    unsigned a0 = __shfl(pA0, sp, 64),      a1 = __shfl(pA1, sp, 64);
                    unsigned a2 = __shfl(pA0, sp + 16, 64), a3 = __shfl(pA1, sp + 16, 64);
                    unsigned b0 = __shfl(pB0, sp, 64),      b1 = __shfl(pB1, sp, 64);
                    unsigned b2 = __shfl(pB0, sp + 16, 64), b3 = __shfl(pB1, sp + 16, 64);
                    bf16x8 pf = (kg & 2) ? mk8(b0, b1, b2, b3) : mk8(a0, a1, a2, a3);
                    oacc = MFMA16(vv, pf, oacc);        // O^T = V^T * P^T
                }
                // o packs as [t][d] ushort4; overwrites q cols of this row range
                ushort4 po;
                po.x = f2bf(oacc[0]); po.y = f2bf(oacc[1]);
                po.z = f2bf(oacc[2]); po.w = f2bf(oacc[3]);
                *(ushort4*)(qs + qrow * QS_S + h * 16 + kg * 4) = po;
            }
        }
        __syncthreads();

        // ========= Phase C: out-proj + residual + LN1 (acc[4] per wave) =====
        {
            bf16x8 wof[4];
            #pragma unroll
            for (int ks = 0; ks < 4; ++ks)
                wof[ks] = *(const bf16x8*)(w_out + (size_t)(l * 128 + ct * 16 + l15) * 128
                                           + ks * 32 + kg * 8);
            fx4 ob4 = *(const fx4*)(out_b + l * 128 + ct * 16 + kg * 4);
            fx4 acc[4];
            #pragma unroll
            for (int j = 0; j < 4; ++j) {
                int trow = (hf * 4 + j) * 16 + l15;
                fx4 a = {0.f, 0.f, 0.f, 0.f};
                #pragma unroll
                for (int ks = 0; ks < 4; ++ks) {
                    bf16x8 of = *(const bf16x8*)(qs + trow * QS_S + ks * 32 + kg * 8);
                    a = MFMA16(wof[ks], of, a);     // OUT^T = Wout * O^T
                }
                ushort4 rx = *(const ushort4*)(xs + trow * XS_S + ct * 16 + kg * 4);
                a[0] += ob4[0] + bf2f(rx.x); a[1] += ob4[1] + bf2f(rx.y);
                a[2] += ob4[2] + bf2f(rx.z); a[3] += ob4[3] + bf2f(rx.w);
                acc[j] = a;
                float s  = a[0] + a[1] + a[2] + a[3];
                float qq = a[0]*a[0] + a[1]*a[1] + a[2]*a[2] + a[3]*a[3];
                s  += __shfl_xor(s, 16, 64);  qq += __shfl_xor(qq, 16, 64);
                s  += __shfl_xor(s, 32, 64);  qq += __shfl_xor(qq, 32, 64);
                if (lid < 16) { float2 p; p.x = s; p.y = qq; lnp[ct * 128 + trow] = p; }
            }
            __syncthreads();
            if (tid < 128) {
                float ms = 0.f, mq = 0.f;
                #pragma unroll
                for (int g = 0; g < 8; ++g) {
                    float2 p = lnp[g * 128 + tid];
                    ms += p.x; mq += p.y;
                }
                float mean = ms * 0.0078125f;
                float var  = mq * 0.0078125f - mean * mean;
                float2 m2; m2.x = mean; m2.y = rsqrtf(var + 1e-5f);
                mrp[tid] = m2;
            }
            __syncthreads();
            fx4 g4 = *(const fx4*)(ln1g + l * 128 + ct * 16 + kg * 4);
            fx4 b4 = *(const fx4*)(ln1b + l * 128 + ct * 16 + kg * 4);
            #pragma unroll
            for (int j = 0; j < 4; ++j) {
                int trow = (hf * 4 + j) * 16 + l15;
                float2 m2 = mrp[trow];
                ushort4 px;
                px.x = f2bf((acc[j][0] - m2.x) * m2.y * g4[0] + b4[0]);
                px.y = f2bf((acc[j][1] - m2.x) * m2.y * g4[1] + b4[1]);
                px.z = f2bf((acc[j][2] - m2.x) * m2.y * g4[2] + b4[2]);
                px.w = f2bf((acc[j][3] - m2.x) * m2.y * g4[3] + b4[3]);
                *(ushort4*)(xs + trow * XS_S + ct * 16 + kg * 4) = px;
            }
        }
        __syncthreads();

        // ======== Phase D: FF, 2 chunks of 256; hidden aliases k|v^T ========
        fx4 yacc[4];
        {
            fx4 z = {0.f, 0.f, 0.f, 0.f};
            #pragma unroll
            for (int j = 0; j < 4; ++j) yacc[j] = z;
        }
        #pragma unroll 1
        for (int c = 0; c < 2; ++c) {
            {   // FF1: n-tile w (16 cols), all 8 row-tiles; + bias + relu -> hb
                int frow = l * 512 + c * 256 + w * 16;
                bf16x8 w1f[4];
                #pragma unroll
                for (int ks = 0; ks < 4; ++ks)
                    w1f[ks] = *(const bf16x8*)(w_ff1 + (size_t)(frow + l15) * 128
                                               + ks * 32 + kg * 8);
                fx4 b1f = *(const fx4*)(ff1b + frow + kg * 4);
                #pragma unroll
                for (int tt = 0; tt < 8; ++tt) {
                    int trow = tt * 16 + l15;
                    bf16x8 xf[4];
                    #pragma unroll
                    for (int ks = 0; ks < 4; ++ks)
                        xf[ks] = *(const bf16x8*)(xs + trow * XS_S + ks * 32 + kg * 8);
                    fx4 a = b1f;
                    #pragma unroll
                    for (int ks = 0; ks < 4; ++ks) a = MFMA16(w1f[ks], xf[ks], a);
                    ushort4 ph;
                    ph.x = f2bf(fmaxf(a[0], 0.f)); ph.y = f2bf(fmaxf(a[1], 0.f));
                    ph.z = f2bf(fmaxf(a[2], 0.f)); ph.w = f2bf(fmaxf(a[3], 0.f));
                    *(ushort4*)(hb + trow * HS + w * 16 + kg * 4) = ph;
                }
            }
            __syncthreads();
            {   // FF2 partial accumulate: Y^T = W2 * H^T (col-tile ct, half hf)
                bf16x8 w2f[8];
                #pragma unroll
                for (int k8 = 0; k8 < 8; ++k8)
                    w2f[k8] = *(const bf16x8*)(w_ff2 + (size_t)(l * 128 + ct * 16 + l15) * 512
                                               + c * 256 + k8 * 32 + kg * 8);
                #pragma unroll
                for (int j = 0; j < 4; ++j) {
                    int trow = (hf * 4 + j) * 16 + l15;
                    #pragma unroll
                    for (int k8 = 0; k8 < 8; ++k8) {
                        bf16x8 hfr = *(const bf16x8*)(hb + trow * HS + k8 * 32 + kg * 8);
                        yacc[j] = MFMA16(w2f[k8], hfr, yacc[j]);
                    }
                }
            }
            if (c == 0) __syncthreads();   // protect hidden before chunk 1
        }

        // ========= Phase E: + bias + residual + LayerNorm2 (+ output) =======
        {
            fx4 fb4 = *(const fx4*)(ff2b + l * 128 + ct * 16 + kg * 4);
            #pragma unroll
            for (int j = 0; j < 4; ++j) {
                int trow = (hf * 4 + j) * 16 + l15;
                ushort4 rx = *(const ushort4*)(xs + trow * XS_S + ct * 16 + kg * 4);
                yacc[j][0] += fb4[0] + bf2f(rx.x);
                yacc[j][1] += fb4[1] + bf2f(rx.y);
                yacc[j][2] += fb4[2] + bf2f(rx.z);
                yacc[j][3] += fb4[3] + bf2f(rx.w);
                fx4 a = yacc[j];
                float s  = a[0] + a[1] + a[2] + a[3];
                float qq = a[0]*a[0] + a[1]*a[1] + a[2]*a[2] + a[3]*a[3];
                s  += __shfl_xor(s, 16, 64);  qq += __shfl_xor(qq, 16, 64);
                s  += __shfl_xor(s, 32, 64);  qq += __shfl_xor(qq, 32, 64);
                if (lid < 16) { float2 p; p.x = s; p.y = qq; lnp[ct * 128 + trow] = p; }
            }
            __syncthreads();
            if (tid < 128) {
                float ms = 0.f, mq = 0.f;
                #pragma unroll
                for (int g = 0; g < 8; ++g) {
                    float2 p = lnp[g * 128 + tid];
                    ms += p.x; mq += p.y;
                }
                float mean = ms * 0.0078125f;
                float var  = mq * 0.0078125f - mean * mean;
                float2 m2; m2.x = mean; m2.y = rsqrtf(var + 1e-5f);
                mrp[tid] = m2;
            }
            __syncthreads();
            fx4 g4 = *(const fx4*)(ln2g + l * 128 + ct * 16 + kg * 4);
            fx4 b4 = *(const fx4*)(ln2b + l * 128 + ct * 16 + kg * 4);
            if (l == 1) {   // final layer: fp32 output, packed float4 stores
                float* op = out + (size_t)b * 16384;
                #pragma unroll
                for (int j = 0; j < 4; ++j) {
                    int trow = (hf * 4 + j) * 16 + l15;
                    float2 m2 = mrp[trow];
                    float4 v4;
                    v4.x = (yacc[j][0] - m2.x) * m2.y * g4[0] + b4[0];
                    v4.y = (yacc[j][1] - m2.x) * m2.y * g4[1] + b4[1];
                    v4.z = (yacc[j][2] - m2.x) * m2.y * g4[2] + b4[2];
                    v4.w = (yacc[j][3] - m2.x) * m2.y * g4[3] + b4[3];
                    *(float4*)(op + (size_t)trow * 128 + ct * 16 + kg * 4) = v4;
                }
            } else {
                #pragma unroll
                for (int j = 0; j < 4; ++j) {
                    int trow = (hf * 4 + j) * 16 + l15;
                    float2 m2 = mrp[trow];
                    ushort4 px;
                    px.x = f2bf((yacc[j][0] - m2.x) * m2.y * g4[0] + b4[0]);
                    px.y = f2bf((yacc[j][1] - m2.x) * m2.y * g4[1] + b4[1]);
                    px.z = f2bf((yacc[j][2] - m2.x) * m2.y * g4[2] + b4[2]);
                    px.w = f2bf((yacc[j][3] - m2.x) * m2.y * g4[3] + b4[3]);
                    *(ushort4*)(xs + trow * XS_S + ct * 16 + kg * 4) = px;
                }
                __syncthreads();   // xs stable before next layer's Phase A
            }
        }
    }
}

// --------------------------------------------------------------------------
extern "C" void kernel_launch(void* const* d_in, const int* in_sizes, int n_in,
                              void* d_out, int out_size, void* d_ws, size_t ws_size,
                              hipStream_t stream) {
    const float* x    = (const float*)d_in[0];
    const float* mask = (const float*)d_in[1];
    const float* w_in = (const float*)d_in[2];
    const float* b_in = (const float*)d_in[3];
    const float* w_o  = (const float*)d_in[4];
    const float* b_o  = (const float*)d_in[5];
    const float* g1   = (const float*)d_in[6];
    const float* bb1  = (const float*)d_in[7];
    const float* w1   = (const float*)d_in[8];
    const float* b1   = (const float*)d_in[9];
    const float* w2   = (const float*)d_in[10];
    const float* b2   = (const float*)d_in[11];
    const float* g2   = (const float*)d_in[12];
    const float* bb2  = (const float*)d_in[13];

    unsigned short* ws = (unsigned short*)d_ws;   // bf16 weights, 786432 B
    prep_weights_bf16<<<1536, 256, 0, stream>>>(w_in, w_o, w1, w2, ws);
    fused_transformer<<<1024, 1024, 0, stream>>>(
        x, mask, b_in, b_o, g1, bb1, b1, b2, g2, bb2,
        ws,                 // in_proj  [L][384][128]
        ws + 98304,         // out_w    [L][128][128]
        ws + 131072,        // ff1_w    [L][512][128]
        ws + 262144,        // ff2_w    [L][128][512]
        (float*)d_out);
}

// Round 6
// 463.273 us; speedup vs baseline: 1.1403x; 1.1403x over previous
//
#include <hip/hip_runtime.h>

// ============================================================================
// Fused 2-layer transformer encoder (B=1024, T=128, D=128, H=8, HD=16, FF=512)
// One workgroup per batch element; bf16 MFMA 16x16x32; fp32 accum/softmax/LN.
// All matmuls in transposed orientation (Y^T = W*X^T) -> ushort4 C-stores.
//
// Occupancy revision 4: keep the 1024-thread block (16 waves -> 4 waves/SIMD,
// occ ~47% proven in R5) and fit the 64-arch-VGPR half of the unified file
// (1024 threads => 128 total regs => compiler splits 64 arch + 64 acc):
//  - NO K-fragment hoist: K A-fragments re-read from LDS per (qt,kt)
//    (the R5 hoist alone was 32 arch regs -> spill).
//  - mask staged once into LDS as bf16 (no per-layer global reads, no mreg).
//  - max-free softmax: scores are O(1) (LN'd inputs x 1/sqrt(D) weights),
//    exp cannot overflow; masked keys exp(-1e9)=0. Saves ~70 VALU/q-tile + 2
//    shuffles; P normalization folded into oacc (4 muls instead of 32).
//  - FF in 4 chunks of 128 so only w2f[4] (16 regs) co-live; Phase A task
//    loop forced unroll-1 so only one 16-reg weight set live at a time.
// Work split: A: 48 (tile,half) tasks, 3/wave. B: head=w>>1, 4 q-tiles.
// C/E: col-tile=w>>1, row-half=w&1. FF1/FF2: (col-tile, half).
// ============================================================================

typedef __attribute__((ext_vector_type(8))) __bf16 bf16x8;
typedef __attribute__((ext_vector_type(4))) float fx4;

#define MFMA16(a, b, c) __builtin_amdgcn_mfma_f32_16x16x32_bf16((a), (b), (c), 0, 0, 0)

// padded LDS strides (elements); dword stride ≡ 4 mod 32
#define XS_S 136
#define QS_S 136
#define KS_S 136
#define VT_S 136
#define HB_S 136

static __device__ __forceinline__ unsigned short f2bf(float f) {
    __bf16 b = (__bf16)f;                       // fptrunc f32->bf16, RTN-even
    return __builtin_bit_cast(unsigned short, b);
}
static __device__ __forceinline__ float bf2f(unsigned short u) {
    return (float)__builtin_bit_cast(__bf16, u);
}
static __device__ __forceinline__ unsigned pk2(float a, float b) {
    return (unsigned)f2bf(a) | ((unsigned)f2bf(b) << 16);
}
static __device__ __forceinline__ bf16x8 mk8(unsigned d0, unsigned d1,
                                             unsigned d2, unsigned d3) {
    union { unsigned u[4]; bf16x8 v; } c;
    c.u[0] = d0; c.u[1] = d1; c.u[2] = d2; c.u[3] = d3;
    return c.v;
}

// --------------------------------------------------------------------------
// Prep: convert all fp32 weights to bf16 into workspace.
// Segments (elements): in_proj 98304 | out 32768 | ff1 131072 | ff2 131072
// --------------------------------------------------------------------------
extern "C" __global__ void prep_weights_bf16(const float* __restrict__ w_in,
                                             const float* __restrict__ w_out,
                                             const float* __restrict__ w_ff1,
                                             const float* __restrict__ w_ff2,
                                             unsigned short* __restrict__ ws) {
    int i = blockIdx.x * 256 + threadIdx.x;     // grid covers exactly 393216
    float v;
    if (i < 98304)       v = w_in[i];
    else if (i < 131072) v = w_out[i - 98304];
    else if (i < 262144) v = w_ff1[i - 131072];
    else                 v = w_ff2[i - 262144];
    ws[i] = f2bf(v);
}

// --------------------------------------------------------------------------
// Main fused kernel. block = 1024 threads = 16 waves. grid = 1024 (one per b).
// 1024 threads => 4 waves/SIMD resident => 128-reg cap (64 arch + 64 acc).
// --------------------------------------------------------------------------
extern "C" __global__ void __launch_bounds__(1024, 1)
fused_transformer(const float* __restrict__ x,
                  const float* __restrict__ mask,
                  const float* __restrict__ inp_b,
                  const float* __restrict__ out_b,
                  const float* __restrict__ ln1g, const float* __restrict__ ln1b,
                  const float* __restrict__ ff1b, const float* __restrict__ ff2b,
                  const float* __restrict__ ln2g, const float* __restrict__ ln2b,
                  const unsigned short* __restrict__ w_inp,
                  const unsigned short* __restrict__ w_out,
                  const unsigned short* __restrict__ w_ff1,
                  const unsigned short* __restrict__ w_ff2,
                  float* __restrict__ out) {
    // ~146 KiB static LDS (one 16-wave block per CU)
    __shared__ __align__(16) unsigned short xs[128 * XS_S];      // x / LN out [t][d]
    __shared__ __align__(16) unsigned short qs[128 * QS_S];      // q -> o     [t][d]
    __shared__ __align__(16) unsigned short kvh[2 * 128 * KS_S]; // k | v^T ; FF hidden
    __shared__ __align__(16) float lnbuf[2304];                  // LN scratch, 9 KiB
    __shared__ __align__(16) unsigned short mlds[128];           // mask (bf16)

    unsigned short* ksb = kvh;                 // k   [t][d]    stride KS_S
    unsigned short* vtb = kvh + 128 * KS_S;    // v^T [d][t]    stride VT_S
    unsigned short* hb  = kvh;                 // FF hidden [t][128] stride HB_S
    float2* lnp = (float2*)lnbuf;              // [8][128] {sum, sumsq}
    float2* mrp = lnp + 1024;                  // [128] {mean, rstd}

    const int tid = threadIdx.x;
    const int w   = tid >> 6;        // wave 0..15
    const int lid = tid & 63;
    const int l15 = lid & 15;
    const int kg  = lid >> 4;        // k-group 0..3
    const int b   = blockIdx.x;
    const int ct  = w >> 1;          // col-tile 0..7 (B/C/E/FF); head in B
    const int hf  = w & 1;           // row half 0/1

    // ---- stage x[b] (fp32) -> xs (bf16), and mask[b] -> mlds (bf16) ----
    const float* xb = x + (size_t)b * 16384;
    #pragma unroll
    for (int i = 0; i < 4; ++i) {
        int e = i * 4096 + tid * 4;
        float4 v4 = *(const float4*)(xb + e);
        int row = e >> 7, col = e & 127;
        ushort4 pk;
        pk.x = f2bf(v4.x); pk.y = f2bf(v4.y); pk.z = f2bf(v4.z); pk.w = f2bf(v4.w);
        *(ushort4*)(xs + row * XS_S + col) = pk;
    }
    if (tid < 128) mlds[tid] = f2bf(mask[b * 128 + tid]);
    __syncthreads();

    for (int l = 0; l < 2; ++l) {
        // ========== Phase A: QKV projection, 48 (tile,half) tasks, 3/wave ===
        {
            const unsigned short* wbase = w_inp + (size_t)l * 49152;
            #pragma unroll 1
            for (int i = 0; i < 3; ++i) {
                int T = w * 3 + i;                 // wave-uniform task id 0..47
                int tile = T >> 1, half = T & 1;   // tile: 0-7 q, 8-15 k, 16-23 v
                bf16x8 wf[4];
                #pragma unroll
                for (int ks = 0; ks < 4; ++ks)
                    wf[ks] = *(const bf16x8*)(wbase + (tile * 16 + l15) * 128
                                              + ks * 32 + kg * 8);
                if (tile < 16) {                   // q or k: Y^T = W * X^T
                    fx4 bs = *(const fx4*)(inp_b + l * 384 + tile * 16 + kg * 4);
                    #pragma unroll
                    for (int j = 0; j < 4; ++j) {
                        int trow = (half * 4 + j) * 16 + l15;
                        bf16x8 xf[4];
                        #pragma unroll
                        for (int ks = 0; ks < 4; ++ks)
                            xf[ks] = *(const bf16x8*)(xs + trow * XS_S + ks * 32 + kg * 8);
                        fx4 a = bs;
                        #pragma unroll
                        for (int ks = 0; ks < 4; ++ks) a = MFMA16(wf[ks], xf[ks], a);
                        ushort4 p4;
                        if (tile < 8) {            // q, pre-scaled by 0.25
                            p4.x = f2bf(a[0] * 0.25f); p4.y = f2bf(a[1] * 0.25f);
                            p4.z = f2bf(a[2] * 0.25f); p4.w = f2bf(a[3] * 0.25f);
                            *(ushort4*)(qs + trow * QS_S + tile * 16 + kg * 4) = p4;
                        } else {                   // k
                            p4.x = f2bf(a[0]); p4.y = f2bf(a[1]);
                            p4.z = f2bf(a[2]); p4.w = f2bf(a[3]);
                            *(ushort4*)(ksb + trow * KS_S + (tile - 8) * 16 + kg * 4) = p4;
                        }
                    }
                } else {                           // v: V = X * Wv^T -> v^T store
                    float bv = inp_b[l * 384 + tile * 16 + l15];
                    #pragma unroll
                    for (int j = 0; j < 4; ++j) {
                        int mt = half * 4 + j;
                        int trow = mt * 16 + l15;
                        bf16x8 xf[4];
                        #pragma unroll
                        for (int ks = 0; ks < 4; ++ks)
                            xf[ks] = *(const bf16x8*)(xs + trow * XS_S + ks * 32 + kg * 8);
                        fx4 a = {bv, bv, bv, bv};
                        #pragma unroll
                        for (int ks = 0; ks < 4; ++ks) a = MFMA16(xf[ks], wf[ks], a);
                        ushort4 p4;
                        p4.x = f2bf(a[0]); p4.y = f2bf(a[1]);
                        p4.z = f2bf(a[2]); p4.w = f2bf(a[3]);
                        *(ushort4*)(vtb + ((tile - 16) * 16 + l15) * VT_S
                                    + mt * 16 + kg * 4) = p4;
                    }
                }
            }
        }
        __syncthreads();

        // ========== Phase B: attention, head = ct, 4 q-tiles per wave =======
        {
            const int h = ct;
            const int sp = (2 * (kg & 1)) * 16 + l15;   // P gather src base
            #pragma unroll 1
            for (int j = 0; j < 4; ++j) {
                int qrow = (hf * 4 + j) * 16 + l15;
                bf16x8 qf = {};
                if (kg < 2) qf = *(const bf16x8*)(qs + qrow * QS_S + h * 16 + kg * 8);
                else if (kg == 2) qf[0] = (__bf16)1.0f;   // ones column -> adds mask
                // S^T tile: lane l15 = query, 32 regs = keys (scaled+masked);
                // K A-fragment read from LDS per kt (no 32-reg hoist)
                fx4 sc[8];
                #pragma unroll
                for (int kt = 0; kt < 8; ++kt) {
                    bf16x8 kf = {};
                    if (kg < 2)
                        kf = *(const bf16x8*)(ksb + (kt * 16 + l15) * KS_S + h * 16 + kg * 8);
                    else if (kg == 2)
                        kf[0] = __builtin_bit_cast(__bf16, mlds[kt * 16 + l15]);
                    fx4 z = {0.f, 0.f, 0.f, 0.f};
                    sc[kt] = MFMA16(kf, qf, z);
                }
                // max-free softmax: per-lane exp+sum over 32 regs + 2 shuffles
                float sm = 0.f;
                #pragma unroll
                for (int kt = 0; kt < 8; ++kt)
                    #pragma unroll
                    for (int r = 0; r < 4; ++r) {
                        float e = __expf(sc[kt][r]);
                        sc[kt][r] = e;
                        sm += e;
                    }
                sm += __shfl_xor(sm, 16, 64);
                sm += __shfl_xor(sm, 32, 64);
                float inv = 1.f / sm;
                // PV: per 32-key step, gather P^T fragment via 8 shuffles
                fx4 oacc = {0.f, 0.f, 0.f, 0.f};
                #pragma unroll
                for (int s = 0; s < 4; ++s) {
                    bf16x8 vv = *(const bf16x8*)(vtb + (h * 16 + l15) * VT_S
                                                 + s * 32 + kg * 8);
                    unsigned pA0 = pk2(sc[2*s][0],   sc[2*s][1]);
                    unsigned pA1 = pk2(sc[2*s][2],   sc[2*s][3]);
                    unsigned pB0 = pk2(sc[2*s+1][0], sc[2*s+1][1]);
                    unsigned pB1 = pk2(sc[2*s+1][2], sc[2*s+1][3]);
                    unsigned a0 = __shfl(pA0, sp, 64),      a1 = __shfl(pA1, sp, 64);
                    unsigned a2 = __shfl(pA0, sp + 16, 64), a3 = __shfl(pA1, sp + 16, 64);
                    unsigned b0 = __shfl(pB0, sp, 64),      b1 = __shfl(pB1, sp, 64);
                    unsigned b2 = __shfl(pB0, sp + 16, 64), b3 = __shfl(pB1, sp + 16, 64);
                    bf16x8 pf = (kg & 2) ? mk8(b0, b1, b2, b3) : mk8(a0, a1, a2, a3);
                    oacc = MFMA16(vv, pf, oacc);        // O^T = V^T * P^T (unnormalized)
                }
                // normalize at the end (lane l15 = query for both inv and oacc)
                ushort4 po;
                po.x = f2bf(oacc[0] * inv); po.y = f2bf(oacc[1] * inv);
                po.z = f2bf(oacc[2] * inv); po.w = f2bf(oacc[3] * inv);
                *(ushort4*)(qs + qrow * QS_S + h * 16 + kg * 4) = po;
            }
        }
        __syncthreads();

        // ========= Phase C: out-proj + residual + LN1 (acc[4] per wave) =====
        {
            bf16x8 wof[4];
            #pragma unroll
            for (int ks = 0; ks < 4; ++ks)
                wof[ks] = *(const bf16x8*)(w_out + (size_t)(l * 128 + ct * 16 + l15) * 128
                                           + ks * 32 + kg * 8);
            fx4 ob4 = *(const fx4*)(out_b + l * 128 + ct * 16 + kg * 4);
            fx4 acc[4];
            #pragma unroll
            for (int j = 0; j < 4; ++j) {
                int trow = (hf * 4 + j) * 16 + l15;
                fx4 a = {0.f, 0.f, 0.f, 0.f};
                #pragma unroll
                for (int ks = 0; ks < 4; ++ks) {
                    bf16x8 of = *(const bf16x8*)(qs + trow * QS_S + ks * 32 + kg * 8);
                    a = MFMA16(wof[ks], of, a);     // OUT^T = Wout * O^T
                }
                ushort4 rx = *(const ushort4*)(xs + trow * XS_S + ct * 16 + kg * 4);
                a[0] += ob4[0] + bf2f(rx.x); a[1] += ob4[1] + bf2f(rx.y);
                a[2] += ob4[2] + bf2f(rx.z); a[3] += ob4[3] + bf2f(rx.w);
                acc[j] = a;
                float s  = a[0] + a[1] + a[2] + a[3];
                float qq = a[0]*a[0] + a[1]*a[1] + a[2]*a[2] + a[3]*a[3];
                s  += __shfl_xor(s, 16, 64);  qq += __shfl_xor(qq, 16, 64);
                s  += __shfl_xor(s, 32, 64);  qq += __shfl_xor(qq, 32, 64);
                if (lid < 16) { float2 p; p.x = s; p.y = qq; lnp[ct * 128 + trow] = p; }
            }
            __syncthreads();
            if (tid < 128) {
                float ms = 0.f, mq = 0.f;
                #pragma unroll
                for (int g = 0; g < 8; ++g) {
                    float2 p = lnp[g * 128 + tid];
                    ms += p.x; mq += p.y;
                }
                float mean = ms * 0.0078125f;
                float var  = mq * 0.0078125f - mean * mean;
                float2 m2; m2.x = mean; m2.y = rsqrtf(var + 1e-5f);
                mrp[tid] = m2;
            }
            __syncthreads();
            fx4 g4 = *(const fx4*)(ln1g + l * 128 + ct * 16 + kg * 4);
            fx4 b4 = *(const fx4*)(ln1b + l * 128 + ct * 16 + kg * 4);
            #pragma unroll
            for (int j = 0; j < 4; ++j) {
                int trow = (hf * 4 + j) * 16 + l15;
                float2 m2 = mrp[trow];
                ushort4 px;
                px.x = f2bf((acc[j][0] - m2.x) * m2.y * g4[0] + b4[0]);
                px.y = f2bf((acc[j][1] - m2.x) * m2.y * g4[1] + b4[1]);
                px.z = f2bf((acc[j][2] - m2.x) * m2.y * g4[2] + b4[2]);
                px.w = f2bf((acc[j][3] - m2.x) * m2.y * g4[3] + b4[3]);
                *(ushort4*)(xs + trow * XS_S + ct * 16 + kg * 4) = px;
            }
        }
        __syncthreads();

        // ======== Phase D: FF, 4 chunks of 128; hidden aliases k|v^T ========
        fx4 yacc[4];
        {
            fx4 z = {0.f, 0.f, 0.f, 0.f};
            #pragma unroll
            for (int j = 0; j < 4; ++j) yacc[j] = z;
        }
        #pragma unroll 1
        for (int c = 0; c < 4; ++c) {
            {   // FF1: wave (ct,hf) -> cols ct*16, rows hf-half; + bias + relu
                int frow = l * 512 + c * 128 + ct * 16;
                bf16x8 w1f[4];
                #pragma unroll
                for (int ks = 0; ks < 4; ++ks)
                    w1f[ks] = *(const bf16x8*)(w_ff1 + (size_t)(frow + l15) * 128
                                               + ks * 32 + kg * 8);
                fx4 b1f = *(const fx4*)(ff1b + frow + kg * 4);
                #pragma unroll
                for (int j = 0; j < 4; ++j) {
                    int trow = (hf * 4 + j) * 16 + l15;
                    bf16x8 xf[4];
                    #pragma unroll
                    for (int ks = 0; ks < 4; ++ks)
                        xf[ks] = *(const bf16x8*)(xs + trow * XS_S + ks * 32 + kg * 8);
                    fx4 a = b1f;
                    #pragma unroll
                    for (int ks = 0; ks < 4; ++ks) a = MFMA16(w1f[ks], xf[ks], a);
                    ushort4 ph;
                    ph.x = f2bf(fmaxf(a[0], 0.f)); ph.y = f2bf(fmaxf(a[1], 0.f));
                    ph.z = f2bf(fmaxf(a[2], 0.f)); ph.w = f2bf(fmaxf(a[3], 0.f));
                    *(ushort4*)(hb + trow * HB_S + ct * 16 + kg * 4) = ph;
                }
            }
            __syncthreads();
            {   // FF2 partial accumulate: Y^T = W2 * H^T (col-tile ct, half hf)
                bf16x8 w2f[4];
                #pragma unroll
                for (int k8 = 0; k8 < 4; ++k8)
                    w2f[k8] = *(const bf16x8*)(w_ff2 + (size_t)(l * 128 + ct * 16 + l15) * 512
                                               + c * 128 + k8 * 32 + kg * 8);
                #pragma unroll
                for (int j = 0; j < 4; ++j) {
                    int trow = (hf * 4 + j) * 16 + l15;
                    #pragma unroll
                    for (int k8 = 0; k8 < 4; ++k8) {
                        bf16x8 hfr = *(const bf16x8*)(hb + trow * HB_S + k8 * 32 + kg * 8);
                        yacc[j] = MFMA16(w2f[k8], hfr, yacc[j]);
                    }
                }
            }
            if (c < 3) __syncthreads();   // protect hidden before next chunk
        }

        // ========= Phase E: + bias + residual + LayerNorm2 (+ output) =======
        {
            fx4 fb4 = *(const fx4*)(ff2b + l * 128 + ct * 16 + kg * 4);
            #pragma unroll
            for (int j = 0; j < 4; ++j) {
                int trow = (hf * 4 + j) * 16 + l15;
                ushort4 rx = *(const ushort4*)(xs + trow * XS_S + ct * 16 + kg * 4);
                yacc[j][0] += fb4[0] + bf2f(rx.x);
                yacc[j][1] += fb4[1] + bf2f(rx.y);
                yacc[j][2] += fb4[2] + bf2f(rx.z);
                yacc[j][3] += fb4[3] + bf2f(rx.w);
                fx4 a = yacc[j];
                float s  = a[0] + a[1] + a[2] + a[3];
                float qq = a[0]*a[0] + a[1]*a[1] + a[2]*a[2] + a[3]*a[3];
                s  += __shfl_xor(s, 16, 64);  qq += __shfl_xor(qq, 16, 64);
                s  += __shfl_xor(s, 32, 64);  qq += __shfl_xor(qq, 32, 64);
                if (lid < 16) { float2 p; p.x = s; p.y = qq; lnp[ct * 128 + trow] = p; }
            }
            __syncthreads();
            if (tid < 128) {
                float ms = 0.f, mq = 0.f;
                #pragma unroll
                for (int g = 0; g < 8; ++g) {
                    float2 p = lnp[g * 128 + tid];
                    ms += p.x; mq += p.y;
                }
                float mean = ms * 0.0078125f;
                float var  = mq * 0.0078125f - mean * mean;
                float2 m2; m2.x = mean; m2.y = rsqrtf(var + 1e-5f);
                mrp[tid] = m2;
            }
            __syncthreads();
            fx4 g4 = *(const fx4*)(ln2g + l * 128 + ct * 16 + kg * 4);
            fx4 b4 = *(const fx4*)(ln2b + l * 128 + ct * 16 + kg * 4);
            if (l == 1) {   // final layer: fp32 output, packed float4 stores
                float* op = out + (size_t)b * 16384;
                #pragma unroll
                for (int j = 0; j < 4; ++j) {
                    int trow = (hf * 4 + j) * 16 + l15;
                    float2 m2 = mrp[trow];
                    float4 v4;
                    v4.x = (yacc[j][0] - m2.x) * m2.y * g4[0] + b4[0];
                    v4.y = (yacc[j][1] - m2.x) * m2.y * g4[1] + b4[1];
                    v4.z = (yacc[j][2] - m2.x) * m2.y * g4[2] + b4[2];
                    v4.w = (yacc[j][3] - m2.x) * m2.y * g4[3] + b4[3];
                    *(float4*)(op + (size_t)trow * 128 + ct * 16 + kg * 4) = v4;
                }
            } else {
                #pragma unroll
                for (int j = 0; j < 4; ++j) {
                    int trow = (hf * 4 + j) * 16 + l15;
                    float2 m2 = mrp[trow];
                    ushort4 px;
                    px.x = f2bf((yacc[j][0] - m2.x) * m2.y * g4[0] + b4[0]);
                    px.y = f2bf((yacc[j][1] - m2.x) * m2.y * g4[1] + b4[1]);
                    px.z = f2bf((yacc[j][2] - m2.x) * m2.y * g4[2] + b4[2]);
                    px.w = f2bf((yacc[j][3] - m2.x) * m2.y * g4[3] + b4[3]);
                    *(ushort4*)(xs + trow * XS_S + ct * 16 + kg * 4) = px;
                }
                __syncthreads();   // xs stable before next layer's Phase A
            }
        }
    }
}

// --------------------------------------------------------------------------
extern "C" void kernel_launch(void* const* d_in, const int* in_sizes, int n_in,
                              void* d_out, int out_size, void* d_ws, size_t ws_size,
                              hipStream_t stream) {
    const float* x    = (const float*)d_in[0];
    const float* mask = (const float*)d_in[1];
    const float* w_in = (const float*)d_in[2];
    const float* b_in = (const float*)d_in[3];
    const float* w_o  = (const float*)d_in[4];
    const float* b_o  = (const float*)d_in[5];
    const float* g1   = (const float*)d_in[6];
    const float* bb1  = (const float*)d_in[7];
    const float* w1   = (const float*)d_in[8];
    const float* b1   = (const float*)d_in[9];
    const float* w2   = (const float*)d_in[10];
    const float* b2   = (const float*)d_in[11];
    const float* g2   = (const float*)d_in[12];
    const float* bb2  = (const float*)d_in[13];

    unsigned short* ws = (unsigned short*)d_ws;   // bf16 weights, 786432 B
    prep_weights_bf16<<<1536, 256, 0, stream>>>(w_in, w_o, w1, w2, ws);
    fused_transformer<<<1024, 1024, 0, stream>>>(
        x, mask, b_in, b_o, g1, bb1, b1, b2, g2, bb2,
        ws,                 // in_proj  [L][384][128]
        ws + 98304,         // out_w    [L][128][128]
        ws + 131072,        // ff1_w    [L][512][128]
        ws + 262144,        // ff2_w    [L][128][512]
        (float*)d_out);
}

// Round 7
// 460.204 us; speedup vs baseline: 1.1479x; 1.0067x over previous
//
#include <hip/hip_runtime.h>

// ============================================================================
// Fused 2-layer transformer encoder (B=1024, T=128, D=128, H=8, HD=16, FF=512)
// One workgroup per batch element; bf16 MFMA 16x16x32; fp32 accum/softmax/LN.
// All matmuls in transposed orientation (Y^T = W*X^T) -> ushort4 C-stores.
//
// DS-pipe revision (R6 post-mortem: DS pipe ~75% busy => throughput bound):
//  - ZERO-SHUFFLE PV: K rows are read in a permuted order
//    (MFMA kt, row m <-> key (kt>>1)*32 + (kt&1)*4 + (m>>2)*8 + (m&3)) so the
//    QK^T C-fragment lands with lane kg holding exactly keys kg*8..kg*8+7 of
//    each 32-key step == the PV B-fragment layout. The P handoff becomes a
//    pure in-register pack (4 dwords), removing all 2048 ds_bpermute per
//    block-layer. V stays in plain column order (already matches); the mask
//    uses the permuted index. Softmax is order-invariant.
//  - FF: 2 chunks of 256 with FF1 register-blocked over 2 col-tiles
//    (w1f[2][4] = 32 regs), halving FF1's xs re-reads and FF barriers.
//    Hidden buffer stride 264 (16B-aligned rows, 2-way-free banks).
// Everything else identical to the R6-verified kernel (64-arch fit, no
// spills, 16-wave block, occ ~46%).
// ============================================================================

typedef __attribute__((ext_vector_type(8))) __bf16 bf16x8;
typedef __attribute__((ext_vector_type(4))) float fx4;

#define MFMA16(a, b, c) __builtin_amdgcn_mfma_f32_16x16x32_bf16((a), (b), (c), 0, 0, 0)

// padded LDS strides (elements)
#define XS_S 136
#define QS_S 136
#define KS_S 136
#define VT_S 136
#define HS2  264     // FF hidden [128][264] (aliases kvh; 16B-aligned rows)

static __device__ __forceinline__ unsigned short f2bf(float f) {
    __bf16 b = (__bf16)f;                       // fptrunc f32->bf16, RTN-even
    return __builtin_bit_cast(unsigned short, b);
}
static __device__ __forceinline__ float bf2f(unsigned short u) {
    return (float)__builtin_bit_cast(__bf16, u);
}
static __device__ __forceinline__ unsigned pk2(float a, float b) {
    return (unsigned)f2bf(a) | ((unsigned)f2bf(b) << 16);
}
static __device__ __forceinline__ bf16x8 mk8(unsigned d0, unsigned d1,
                                             unsigned d2, unsigned d3) {
    union { unsigned u[4]; bf16x8 v; } c;
    c.u[0] = d0; c.u[1] = d1; c.u[2] = d2; c.u[3] = d3;
    return c.v;
}

// --------------------------------------------------------------------------
// Prep: convert all fp32 weights to bf16 into workspace.
// Segments (elements): in_proj 98304 | out 32768 | ff1 131072 | ff2 131072
// --------------------------------------------------------------------------
extern "C" __global__ void prep_weights_bf16(const float* __restrict__ w_in,
                                             const float* __restrict__ w_out,
                                             const float* __restrict__ w_ff1,
                                             const float* __restrict__ w_ff2,
                                             unsigned short* __restrict__ ws) {
    int i = blockIdx.x * 256 + threadIdx.x;     // grid covers exactly 393216
    float v;
    if (i < 98304)       v = w_in[i];
    else if (i < 131072) v = w_out[i - 98304];
    else if (i < 262144) v = w_ff1[i - 131072];
    else                 v = w_ff2[i - 262144];
    ws[i] = f2bf(v);
}

// --------------------------------------------------------------------------
// Main fused kernel. block = 1024 threads = 16 waves. grid = 1024 (one per b).
// 1024 threads => 4 waves/SIMD resident => 128-reg cap (64 arch + 64 acc).
// --------------------------------------------------------------------------
extern "C" __global__ void __launch_bounds__(1024, 1)
fused_transformer(const float* __restrict__ x,
                  const float* __restrict__ mask,
                  const float* __restrict__ inp_b,
                  const float* __restrict__ out_b,
                  const float* __restrict__ ln1g, const float* __restrict__ ln1b,
                  const float* __restrict__ ff1b, const float* __restrict__ ff2b,
                  const float* __restrict__ ln2g, const float* __restrict__ ln2b,
                  const unsigned short* __restrict__ w_inp,
                  const unsigned short* __restrict__ w_out,
                  const unsigned short* __restrict__ w_ff1,
                  const unsigned short* __restrict__ w_ff2,
                  float* __restrict__ out) {
    // ~111 KiB static LDS (one 16-wave block per CU)
    __shared__ __align__(16) unsigned short xs[128 * XS_S];      // x / LN out [t][d]
    __shared__ __align__(16) unsigned short qs[128 * QS_S];      // q -> o     [t][d]
    __shared__ __align__(16) unsigned short kvh[2 * 128 * KS_S]; // k | v^T ; FF hidden
    __shared__ __align__(16) float lnbuf[2304];                  // LN scratch, 9 KiB
    __shared__ __align__(16) unsigned short mlds[128];           // mask (bf16)

    unsigned short* ksb = kvh;                 // k   [t][d]    stride KS_S
    unsigned short* vtb = kvh + 128 * KS_S;    // v^T [d][t]    stride VT_S
    unsigned short* hb  = kvh;                 // FF hidden [t][256] stride HS2
    float2* lnp = (float2*)lnbuf;              // [8][128] {sum, sumsq}
    float2* mrp = lnp + 1024;                  // [128] {mean, rstd}

    const int tid = threadIdx.x;
    const int w   = tid >> 6;        // wave 0..15
    const int lid = tid & 63;
    const int l15 = lid & 15;
    const int kg  = lid >> 4;        // k-group 0..3
    const int b   = blockIdx.x;
    const int ct  = w >> 1;          // col-tile 0..7 (B/C/E/FF2); head in B
    const int hf  = w & 1;           // row half 0/1

    // ---- stage x[b] (fp32) -> xs (bf16), and mask[b] -> mlds (bf16) ----
    const float* xb = x + (size_t)b * 16384;
    #pragma unroll
    for (int i = 0; i < 4; ++i) {
        int e = i * 4096 + tid * 4;
        float4 v4 = *(const float4*)(xb + e);
        int row = e >> 7, col = e & 127;
        ushort4 pk;
        pk.x = f2bf(v4.x); pk.y = f2bf(v4.y); pk.z = f2bf(v4.z); pk.w = f2bf(v4.w);
        *(ushort4*)(xs + row * XS_S + col) = pk;
    }
    if (tid < 128) mlds[tid] = f2bf(mask[b * 128 + tid]);
    __syncthreads();

    for (int l = 0; l < 2; ++l) {
        // ========== Phase A: QKV projection, 48 (tile,half) tasks, 3/wave ===
        {
            const unsigned short* wbase = w_inp + (size_t)l * 49152;
            #pragma unroll 1
            for (int i = 0; i < 3; ++i) {
                int T = w * 3 + i;                 // wave-uniform task id 0..47
                int tile = T >> 1, half = T & 1;   // tile: 0-7 q, 8-15 k, 16-23 v
                bf16x8 wf[4];
                #pragma unroll
                for (int ks = 0; ks < 4; ++ks)
                    wf[ks] = *(const bf16x8*)(wbase + (tile * 16 + l15) * 128
                                              + ks * 32 + kg * 8);
                if (tile < 16) {                   // q or k: Y^T = W * X^T
                    fx4 bs = *(const fx4*)(inp_b + l * 384 + tile * 16 + kg * 4);
                    #pragma unroll
                    for (int j = 0; j < 4; ++j) {
                        int trow = (half * 4 + j) * 16 + l15;
                        bf16x8 xf[4];
                        #pragma unroll
                        for (int ks = 0; ks < 4; ++ks)
                            xf[ks] = *(const bf16x8*)(xs + trow * XS_S + ks * 32 + kg * 8);
                        fx4 a = bs;
                        #pragma unroll
                        for (int ks = 0; ks < 4; ++ks) a = MFMA16(wf[ks], xf[ks], a);
                        ushort4 p4;
                        if (tile < 8) {            // q, pre-scaled by 0.25
                            p4.x = f2bf(a[0] * 0.25f); p4.y = f2bf(a[1] * 0.25f);
                            p4.z = f2bf(a[2] * 0.25f); p4.w = f2bf(a[3] * 0.25f);
                            *(ushort4*)(qs + trow * QS_S + tile * 16 + kg * 4) = p4;
                        } else {                   // k
                            p4.x = f2bf(a[0]); p4.y = f2bf(a[1]);
                            p4.z = f2bf(a[2]); p4.w = f2bf(a[3]);
                            *(ushort4*)(ksb + trow * KS_S + (tile - 8) * 16 + kg * 4) = p4;
                        }
                    }
                } else {                           // v: V = X * Wv^T -> v^T store
                    float bv = inp_b[l * 384 + tile * 16 + l15];
                    #pragma unroll
                    for (int j = 0; j < 4; ++j) {
                        int mt = half * 4 + j;
                        int trow = mt * 16 + l15;
                        bf16x8 xf[4];
                        #pragma unroll
                        for (int ks = 0; ks < 4; ++ks)
                            xf[ks] = *(const bf16x8*)(xs + trow * XS_S + ks * 32 + kg * 8);
                        fx4 a = {bv, bv, bv, bv};
                        #pragma unroll
                        for (int ks = 0; ks < 4; ++ks) a = MFMA16(xf[ks], wf[ks], a);
                        ushort4 p4;
                        p4.x = f2bf(a[0]); p4.y = f2bf(a[1]);
                        p4.z = f2bf(a[2]); p4.w = f2bf(a[3]);
                        *(ushort4*)(vtb + ((tile - 16) * 16 + l15) * VT_S
                                    + mt * 16 + kg * 4) = p4;
                    }
                }
            }
        }
        __syncthreads();

        // ========== Phase B: attention, head = ct, zero-shuffle PV ==========
        {
            const int h = ct;
            // permuted base row: MFMA row m -> key offset (m>>2)*8 + (m&3)
            const int r0 = ((l15 >> 2) << 3) + (l15 & 3);
            #pragma unroll 1
            for (int j = 0; j < 4; ++j) {
                int qrow = (hf * 4 + j) * 16 + l15;
                bf16x8 qf = {};
                if (kg < 2) qf = *(const bf16x8*)(qs + qrow * QS_S + h * 16 + kg * 8);
                else if (kg == 2) qf[0] = (__bf16)1.0f;   // ones column -> adds mask
                // S^T: MFMA kt covers keys (kt>>1)*32 + (kt&1)*4 + {r0-set};
                // resulting C-layout: lane kg, sc[2s][r]=key s*32+kg*8+r,
                //                              sc[2s+1][r]=key s*32+kg*8+4+r.
                fx4 sc[8];
                #pragma unroll
                for (int kt = 0; kt < 8; ++kt) {
                    int krow = (kt >> 1) * 32 + (kt & 1) * 4 + r0;
                    bf16x8 kf = {};
                    if (kg < 2)
                        kf = *(const bf16x8*)(ksb + krow * KS_S + h * 16 + kg * 8);
                    else if (kg == 2)
                        kf[0] = __builtin_bit_cast(__bf16, mlds[krow]);
                    fx4 z = {0.f, 0.f, 0.f, 0.f};
                    sc[kt] = MFMA16(kf, qf, z);
                }
                // max-free softmax: per-lane exp+sum over 32 regs + 2 shuffles
                float sm = 0.f;
                #pragma unroll
                for (int kt = 0; kt < 8; ++kt)
                    #pragma unroll
                    for (int r = 0; r < 4; ++r) {
                        float e = __expf(sc[kt][r]);
                        sc[kt][r] = e;
                        sm += e;
                    }
                sm += __shfl_xor(sm, 16, 64);
                sm += __shfl_xor(sm, 32, 64);
                float inv = 1.f / sm;
                // PV: B-fragment is a pure in-register pack (no shuffles)
                fx4 oacc = {0.f, 0.f, 0.f, 0.f};
                #pragma unroll
                for (int s = 0; s < 4; ++s) {
                    bf16x8 vv = *(const bf16x8*)(vtb + (h * 16 + l15) * VT_S
                                                 + s * 32 + kg * 8);
                    bf16x8 pf = mk8(pk2(sc[2*s][0],   sc[2*s][1]),
                                    pk2(sc[2*s][2],   sc[2*s][3]),
                                    pk2(sc[2*s+1][0], sc[2*s+1][1]),
                                    pk2(sc[2*s+1][2], sc[2*s+1][3]));
                    oacc = MFMA16(vv, pf, oacc);        // O^T = V^T * P^T (unnorm.)
                }
                ushort4 po;
                po.x = f2bf(oacc[0] * inv); po.y = f2bf(oacc[1] * inv);
                po.z = f2bf(oacc[2] * inv); po.w = f2bf(oacc[3] * inv);
                *(ushort4*)(qs + qrow * QS_S + h * 16 + kg * 4) = po;
            }
        }
        __syncthreads();

        // ========= Phase C: out-proj + residual + LN1 (acc[4] per wave) =====
        {
            bf16x8 wof[4];
            #pragma unroll
            for (int ks = 0; ks < 4; ++ks)
                wof[ks] = *(const bf16x8*)(w_out + (size_t)(l * 128 + ct * 16 + l15) * 128
                                           + ks * 32 + kg * 8);
            fx4 ob4 = *(const fx4*)(out_b + l * 128 + ct * 16 + kg * 4);
            fx4 acc[4];
            #pragma unroll
            for (int j = 0; j < 4; ++j) {
                int trow = (hf * 4 + j) * 16 + l15;
                fx4 a = {0.f, 0.f, 0.f, 0.f};
                #pragma unroll
                for (int ks = 0; ks < 4; ++ks) {
                    bf16x8 of = *(const bf16x8*)(qs + trow * QS_S + ks * 32 + kg * 8);
                    a = MFMA16(wof[ks], of, a);     // OUT^T = Wout * O^T
                }
                ushort4 rx = *(const ushort4*)(xs + trow * XS_S + ct * 16 + kg * 4);
                a[0] += ob4[0] + bf2f(rx.x); a[1] += ob4[1] + bf2f(rx.y);
                a[2] += ob4[2] + bf2f(rx.z); a[3] += ob4[3] + bf2f(rx.w);
                acc[j] = a;
                float s  = a[0] + a[1] + a[2] + a[3];
                float qq = a[0]*a[0] + a[1]*a[1] + a[2]*a[2] + a[3]*a[3];
                s  += __shfl_xor(s, 16, 64);  qq += __shfl_xor(qq, 16, 64);
                s  += __shfl_xor(s, 32, 64);  qq += __shfl_xor(qq, 32, 64);
                if (lid < 16) { float2 p; p.x = s; p.y = qq; lnp[ct * 128 + trow] = p; }
            }
            __syncthreads();
            if (tid < 128) {
                float ms = 0.f, mq = 0.f;
                #pragma unroll
                for (int g = 0; g < 8; ++g) {
                    float2 p = lnp[g * 128 + tid];
                    ms += p.x; mq += p.y;
                }
                float mean = ms * 0.0078125f;
                float var  = mq * 0.0078125f - mean * mean;
                float2 m2; m2.x = mean; m2.y = rsqrtf(var + 1e-5f);
                mrp[tid] = m2;
            }
            __syncthreads();
            fx4 g4 = *(const fx4*)(ln1g + l * 128 + ct * 16 + kg * 4);
            fx4 b4 = *(const fx4*)(ln1b + l * 128 + ct * 16 + kg * 4);
            #pragma unroll
            for (int j = 0; j < 4; ++j) {
                int trow = (hf * 4 + j) * 16 + l15;
                float2 m2 = mrp[trow];
                ushort4 px;
                px.x = f2bf((acc[j][0] - m2.x) * m2.y * g4[0] + b4[0]);
                px.y = f2bf((acc[j][1] - m2.x) * m2.y * g4[1] + b4[1]);
                px.z = f2bf((acc[j][2] - m2.x) * m2.y * g4[2] + b4[2]);
                px.w = f2bf((acc[j][3] - m2.x) * m2.y * g4[3] + b4[3]);
                *(ushort4*)(xs + trow * XS_S + ct * 16 + kg * 4) = px;
            }
        }
        __syncthreads();

        // ==== Phase D: FF, 2 chunks of 256; FF1 reg-blocked 2 col-tiles =====
        fx4 yacc[4];
        {
            fx4 z = {0.f, 0.f, 0.f, 0.f};
            #pragma unroll
            for (int j = 0; j < 4; ++j) yacc[j] = z;
        }
        #pragma unroll 1
        for (int c = 0; c < 2; ++c) {
            {   // FF1: wave (tp=w>>1, hf): col-tiles {2tp,2tp+1}, rows hf-half
                const int tp = w >> 1;
                int frow = l * 512 + c * 256 + tp * 32;
                bf16x8 w1f[2][4];
                fx4 b1f[2];
                #pragma unroll
                for (int u = 0; u < 2; ++u) {
                    #pragma unroll
                    for (int ks = 0; ks < 4; ++ks)
                        w1f[u][ks] = *(const bf16x8*)(w_ff1
                                        + (size_t)(frow + u * 16 + l15) * 128
                                        + ks * 32 + kg * 8);
                    b1f[u] = *(const fx4*)(ff1b + frow + u * 16 + kg * 4);
                }
                #pragma unroll
                for (int j = 0; j < 4; ++j) {
                    int trow = (hf * 4 + j) * 16 + l15;
                    bf16x8 xf[4];
                    #pragma unroll
                    for (int ks = 0; ks < 4; ++ks)
                        xf[ks] = *(const bf16x8*)(xs + trow * XS_S + ks * 32 + kg * 8);
                    #pragma unroll
                    for (int u = 0; u < 2; ++u) {
                        fx4 a = b1f[u];
                        #pragma unroll
                        for (int ks = 0; ks < 4; ++ks) a = MFMA16(w1f[u][ks], xf[ks], a);
                        ushort4 ph;
                        ph.x = f2bf(fmaxf(a[0], 0.f)); ph.y = f2bf(fmaxf(a[1], 0.f));
                        ph.z = f2bf(fmaxf(a[2], 0.f)); ph.w = f2bf(fmaxf(a[3], 0.f));
                        *(ushort4*)(hb + trow * HS2 + tp * 32 + u * 16 + kg * 4) = ph;
                    }
                }
            }
            __syncthreads();
            {   // FF2 partial accumulate over this 256-chunk (col-tile ct, hf)
                bf16x8 w2f[8];
                #pragma unroll
                for (int k8 = 0; k8 < 8; ++k8)
                    w2f[k8] = *(const bf16x8*)(w_ff2 + (size_t)(l * 128 + ct * 16 + l15) * 512
                                               + c * 256 + k8 * 32 + kg * 8);
                #pragma unroll
                for (int j = 0; j < 4; ++j) {
                    int trow = (hf * 4 + j) * 16 + l15;
                    #pragma unroll
                    for (int k8 = 0; k8 < 8; ++k8) {
                        bf16x8 hfr = *(const bf16x8*)(hb + trow * HS2 + k8 * 32 + kg * 8);
                        yacc[j] = MFMA16(w2f[k8], hfr, yacc[j]);
                    }
                }
            }
            if (c == 0) __syncthreads();   // protect hidden before chunk 1
        }

        // ========= Phase E: + bias + residual + LayerNorm2 (+ output) =======
        {
            fx4 fb4 = *(const fx4*)(ff2b + l * 128 + ct * 16 + kg * 4);
            #pragma unroll
            for (int j = 0; j < 4; ++j) {
                int trow = (hf * 4 + j) * 16 + l15;
                ushort4 rx = *(const ushort4*)(xs + trow * XS_S + ct * 16 + kg * 4);
                yacc[j][0] += fb4[0] + bf2f(rx.x);
                yacc[j][1] += fb4[1] + bf2f(rx.y);
                yacc[j][2] += fb4[2] + bf2f(rx.z);
                yacc[j][3] += fb4[3] + bf2f(rx.w);
                fx4 a = yacc[j];
                float s  = a[0] + a[1] + a[2] + a[3];
                float qq = a[0]*a[0] + a[1]*a[1] + a[2]*a[2] + a[3]*a[3];
                s  += __shfl_xor(s, 16, 64);  qq += __shfl_xor(qq, 16, 64);
                s  += __shfl_xor(s, 32, 64);  qq += __shfl_xor(qq, 32, 64);
                if (lid < 16) { float2 p; p.x = s; p.y = qq; lnp[ct * 128 + trow] = p; }
            }
            __syncthreads();
            if (tid < 128) {
                float ms = 0.f, mq = 0.f;
                #pragma unroll
                for (int g = 0; g < 8; ++g) {
                    float2 p = lnp[g * 128 + tid];
                    ms += p.x; mq += p.y;
                }
                float mean = ms * 0.0078125f;
                float var  = mq * 0.0078125f - mean * mean;
                float2 m2; m2.x = mean; m2.y = rsqrtf(var + 1e-5f);
                mrp[tid] = m2;
            }
            __syncthreads();
            fx4 g4 = *(const fx4*)(ln2g + l * 128 + ct * 16 + kg * 4);
            fx4 b4 = *(const fx4*)(ln2b + l * 128 + ct * 16 + kg * 4);
            if (l == 1) {   // final layer: fp32 output, packed float4 stores
                float* op = out + (size_t)b * 16384;
                #pragma unroll
                for (int j = 0; j < 4; ++j) {
                    int trow = (hf * 4 + j) * 16 + l15;
                    float2 m2 = mrp[trow];
                    float4 v4;
                    v4.x = (yacc[j][0] - m2.x) * m2.y * g4[0] + b4[0];
                    v4.y = (yacc[j][1] - m2.x) * m2.y * g4[1] + b4[1];
                    v4.z = (yacc[j][2] - m2.x) * m2.y * g4[2] + b4[2];
                    v4.w = (yacc[j][3] - m2.x) * m2.y * g4[3] + b4[3];
                    *(float4*)(op + (size_t)trow * 128 + ct * 16 + kg * 4) = v4;
                }
            } else {
                #pragma unroll
                for (int j = 0; j < 4; ++j) {
                    int trow = (hf * 4 + j) * 16 + l15;
                    float2 m2 = mrp[trow];
                    ushort4 px;
                    px.x = f2bf((yacc[j][0] - m2.x) * m2.y * g4[0] + b4[0]);
                    px.y = f2bf((yacc[j][1] - m2.x) * m2.y * g4[1] + b4[1]);
                    px.z = f2bf((yacc[j][2] - m2.x) * m2.y * g4[2] + b4[2]);
                    px.w = f2bf((yacc[j][3] - m2.x) * m2.y * g4[3] + b4[3]);
                    *(ushort4*)(xs + trow * XS_S + ct * 16 + kg * 4) = px;
                }
                __syncthreads();   // xs stable before next layer's Phase A
            }
        }
    }
}

// --------------------------------------------------------------------------
extern "C" void kernel_launch(void* const* d_in, const int* in_sizes, int n_in,
                              void* d_out, int out_size, void* d_ws, size_t ws_size,
                              hipStream_t stream) {
    const float* x    = (const float*)d_in[0];
    const float* mask = (const float*)d_in[1];
    const float* w_in = (const float*)d_in[2];
    const float* b_in = (const float*)d_in[3];
    const float* w_o  = (const float*)d_in[4];
    const float* b_o  = (const float*)d_in[5];
    const float* g1   = (const float*)d_in[6];
    const float* bb1  = (const float*)d_in[7];
    const float* w1   = (const float*)d_in[8];
    const float* b1   = (const float*)d_in[9];
    const float* w2   = (const float*)d_in[10];
    const float* b2   = (const float*)d_in[11];
    const float* g2   = (const float*)d_in[12];
    const float* bb2  = (const float*)d_in[13];

    unsigned short* ws = (unsigned short*)d_ws;   // bf16 weights, 786432 B
    prep_weights_bf16<<<1536, 256, 0, stream>>>(w_in, w_o, w1, w2, ws);
    fused_transformer<<<1024, 1024, 0, stream>>>(
        x, mask, b_in, b_o, g1, bb1, b1, b2, g2, bb2,
        ws,                 // in_proj  [L][384][128]
        ws + 98304,         // out_w    [L][128][128]
        ws + 131072,        // ff1_w    [L][512][128]
        ws + 262144,        // ff2_w    [L][128][512]
        (float*)d_out);
}